// Round 10
// baseline (252.928 us; speedup 1.0000x reference)
//
#include <hip/hip_runtime.h>

#define N_NODES 100000
#define BSH 9                      // 512 nodes per bucket
#define NBKT ((N_NODES + 511) >> BSH)   // 196
#define CH 7168                    // items per partition chunk (56KB LDS stage)
#define SEGSH 15                   // src segment = src >> 15 (4 segs, <=4MB h1b each)
#define NSEG 4

typedef unsigned int u32;
typedef unsigned short u16;
typedef __attribute__((ext_vector_type(8))) short s8v;   // 8 bf16 (4 VGPRs)
typedef __attribute__((ext_vector_type(4))) float f4v;   // 4 f32 acc

static __device__ __forceinline__ u16 f2bf(float f) {  // round-nearest-even
    union { float f; u32 u; } c; c.f = f;
    u32 r = (c.u + 0x7fffu + ((c.u >> 16) & 1u)) >> 16;
    return (u16)r;
}
static __device__ __forceinline__ float bf2f_u(u16 h) {
    union { u32 u; float f; } c; c.u = ((u32)h) << 16;
    return c.f;
}
static __device__ __forceinline__ void acc2(u32 p, float& a, float& b) {
    union { u32 u; float f; } lo, hi;
    lo.u = p << 16;
    hi.u = p & 0xffff0000u;
    a += lo.f;
    b += hi.f;
}
static __device__ __forceinline__ void acc8(uint4 p, float* a) {
    acc2(p.x, a[0], a[1]); acc2(p.y, a[2], a[3]);
    acc2(p.z, a[4], a[5]); acc2(p.w, a[6], a[7]);
}

// ============ CSR build, bucketed ============
// item e in [0,E) = edge (src[e],dst[e]); e in [E,E+N) = self-loop (v,v).

__global__ __launch_bounds__(256) void coarsehist_k(const int* __restrict__ dst,
        int* __restrict__ ccount, int E, int TOT) {
    __shared__ int hist[256];
    hist[threadIdx.x] = 0;
    __syncthreads();
    int base = blockIdx.x * CH;
    int cnt = min(CH, TOT - base);
    for (int i = threadIdx.x; i < cnt; i += 256) {
        int e = base + i;
        int d = (e < E) ? dst[e] : e - E;
        atomicAdd(&hist[d >> BSH], 1);
    }
    __syncthreads();
    if (hist[threadIdx.x]) atomicAdd(&ccount[threadIdx.x], hist[threadIdx.x]);
}

// single block: scan 196 coarse counts -> cbase[0..NBKT], bcur, offsets[N]
__global__ __launch_bounds__(256) void coarsescan_k(const int* __restrict__ ccount,
        int* __restrict__ cbase, int* __restrict__ bcur, int* __restrict__ offsets) {
    __shared__ int ps[256];
    int t = threadIdx.x;
    int c = (t < NBKT) ? ccount[t] : 0;
    ps[t] = c;
    __syncthreads();
    for (int off = 1; off < 256; off <<= 1) {
        int val = ps[t];
        int add = (t >= off) ? ps[t - off] : 0;
        __syncthreads();
        ps[t] = val + add;
        __syncthreads();
    }
    int incl = ps[t], excl = incl - c;
    if (t < NBKT) cbase[t] = excl;
    bcur[t] = (t < NBKT) ? excl : incl;
    if (t == NBKT - 1) cbase[NBKT] = incl;
    if (t == 255) offsets[N_NODES] = ps[255];
}

// chunked LDS counting-sort partition: items -> bktBuf grouped by bucket.
__global__ __launch_bounds__(256) void partition_k(const int* __restrict__ src,
        const int* __restrict__ dst, int* __restrict__ bcur,
        uint2* __restrict__ bktBuf, int E, int TOT) {
    __shared__ int hist[256];
    __shared__ int lbase[256];
    __shared__ int gbase[256];
    __shared__ int ps[256];
    __shared__ uint2 stage[CH];
    int t = threadIdx.x;
    int base = blockIdx.x * CH;
    int cnt = min(CH, TOT - base);
    hist[t] = 0;
    __syncthreads();
    for (int i = t; i < cnt; i += 256) {
        int e = base + i;
        int d = (e < E) ? dst[e] : e - E;
        atomicAdd(&hist[d >> BSH], 1);
    }
    __syncthreads();
    ps[t] = hist[t];
    __syncthreads();
    for (int off = 1; off < 256; off <<= 1) {
        int val = ps[t];
        int add = (t >= off) ? ps[t - off] : 0;
        __syncthreads();
        ps[t] = val + add;
        __syncthreads();
    }
    lbase[t] = ps[t] - hist[t];
    gbase[t] = atomicAdd(&bcur[t], hist[t]);
    hist[t] = 0;
    __syncthreads();
    for (int i = t; i < cnt; i += 256) {
        int e = base + i;
        int s, d;
        if (e < E) { s = src[e]; d = dst[e]; }
        else       { s = d = e - E; }
        int b = d >> BSH;
        int lpos = lbase[b] + atomicAdd(&hist[b], 1);
        stage[lpos] = make_uint2((u32)s, (u32)d);
    }
    __syncthreads();
    for (int i = t; i < cnt; i += 256) {
        uint2 p = stage[i];
        int b = (int)p.y >> BSH;
        bktBuf[gbase[b] + (i - lbase[b])] = p;
    }
}

// one block per bucket: per-(node,seg) histogram+scan -> offsets, soff, dinv;
// scatter srt_src grouped by (node, src-segment) in a block-exclusive window.
__global__ __launch_bounds__(256) void buildfill_k(const int* __restrict__ cbase,
        const uint2* __restrict__ bktBuf, int* __restrict__ offsets,
        int* __restrict__ soff, float* __restrict__ dinv,
        int* __restrict__ srt_src) {
    __shared__ int hist[2048];
    __shared__ int hscan[2048];
    __shared__ int cur[2048];
    __shared__ int ps[256];
    int t = threadIdx.x;
    int b = blockIdx.x;
    int v0 = b << BSH;
    int nv = min(512, N_NODES - v0);
    for (int k = t; k < 2048; k += 256) { hist[k] = 0; cur[k] = 0; }
    __syncthreads();
    int beg = cbase[b], endi = cbase[b + 1];
    for (int i = beg + t; i < endi; i += 256) {
        uint2 p = bktBuf[i];
        atomicAdd(&hist[(((int)p.y - v0) << 2) | ((int)p.x >> SEGSH)], 1);
    }
    __syncthreads();
    // exclusive scan of hist[0..2047]: 8 per thread + Hillis-Steele over 256
    int loc[8];
    int own = 0;
#pragma unroll
    for (int k = 0; k < 8; ++k) { loc[k] = hist[8 * t + k]; own += loc[k]; }
    ps[t] = own;
    __syncthreads();
    for (int off = 1; off < 256; off <<= 1) {
        int val = ps[t];
        int add = (t >= off) ? ps[t - off] : 0;
        __syncthreads();
        ps[t] = val + add;
        __syncthreads();
    }
    int run = ps[t] - own;
#pragma unroll
    for (int k = 0; k < 8; ++k) { hscan[8 * t + k] = run; run += loc[k]; }
    __syncthreads();
    // offsets + per-seg soff + dinv (counts include the self-loop -> deg+1)
    for (int j = t; j < nv; j += 256) {
        int h4 = j << 2;
        offsets[v0 + j] = beg + hscan[h4];
#pragma unroll
        for (int s = 0; s < 4; ++s)
            soff[(size_t)(v0 + j) * 4 + s] = beg + hscan[h4 + s];
        dinv[v0 + j] = rsqrtf((float)(hist[h4] + hist[h4 + 1]
                                      + hist[h4 + 2] + hist[h4 + 3]));
    }
    // scatter within [beg, endi) — block-exclusive window
    for (int i = beg + t; i < endi; i += 256) {
        uint2 p = bktBuf[i];
        int j2 = (((int)p.y - v0) << 2) | ((int)p.x >> SEGSH);
        int pos = atomicAdd(&cur[j2], 1);
        srt_src[beg + hscan[j2] + pos] = (int)p.x;
    }
}

// ============ GEMM1 (MFMA): h1b[N,64](bf16) = dinv[row] * (x[N,128] @ W1) ====

static __device__ __forceinline__ void split8(const float* __restrict__ xp,
                                              s8v& hi, s8v& lo) {
    float4 v0 = *(const float4*)xp;
    float4 v1 = *(const float4*)(xp + 4);
    float xv[8] = {v0.x, v0.y, v0.z, v0.w, v1.x, v1.y, v1.z, v1.w};
#pragma unroll
    for (int j = 0; j < 8; ++j) {
        u16 h = f2bf(xv[j]);
        hi[j] = (short)h;
        lo[j] = (short)f2bf(xv[j] - bf2f_u(h));
    }
}

__global__ __launch_bounds__(256) void gemm1_k(const float* __restrict__ x,
                                               const float* __restrict__ W1,
                                               const float* __restrict__ dinv,
                                               u16* __restrict__ h1b) {
    __shared__ __attribute__((aligned(16))) short Bs[2][4][4][512];
    int t = threadIdx.x;
    for (int i = t; i < 128 * 64; i += 256) {
        int k = i >> 6, c = i & 63;
        float w = W1[i];
        u16 h = f2bf(w);
        u16 l = f2bf(w - bf2f_u(h));
        int ks = k >> 5, kg = (k >> 3) & 3, kk = k & 7;
        int ct = c >> 4, col = c & 15;
        int idx = (kg * 16 + col) * 8 + kk;
        Bs[0][ks][ct][idx] = (short)h;
        Bs[1][ks][ct][idx] = (short)l;
    }
    __syncthreads();

    int lane = t & 63;
    int rows0 = (blockIdx.x * 4 + (t >> 6)) * 32;
    if (rows0 >= N_NODES) return;

    f4v acc[2][4];
#pragma unroll
    for (int rt = 0; rt < 2; ++rt)
#pragma unroll
        for (int ct = 0; ct < 4; ++ct)
            acc[rt][ct] = (f4v){0.f, 0.f, 0.f, 0.f};

    int arow = lane & 15;
    int kgl = lane >> 4;
#pragma unroll
    for (int ks = 0; ks < 4; ++ks) {
        s8v bh[4], bl[4];
#pragma unroll
        for (int ct = 0; ct < 4; ++ct) {
            bh[ct] = *(const s8v*)&Bs[0][ks][ct][lane * 8];
            bl[ct] = *(const s8v*)&Bs[1][ks][ct][lane * 8];
        }
#pragma unroll
        for (int rt = 0; rt < 2; ++rt) {
            s8v ah, al;
            const float* xp = x + (size_t)(rows0 + rt * 16 + arow) * 128
                                + ks * 32 + kgl * 8;
            split8(xp, ah, al);
#pragma unroll
            for (int ct = 0; ct < 4; ++ct) {
                acc[rt][ct] = __builtin_amdgcn_mfma_f32_16x16x32_bf16(
                    ah, bh[ct], acc[rt][ct], 0, 0, 0);
                acc[rt][ct] = __builtin_amdgcn_mfma_f32_16x16x32_bf16(
                    ah, bl[ct], acc[rt][ct], 0, 0, 0);
                acc[rt][ct] = __builtin_amdgcn_mfma_f32_16x16x32_bf16(
                    al, bh[ct], acc[rt][ct], 0, 0, 0);
            }
        }
    }

#pragma unroll
    for (int rt = 0; rt < 2; ++rt) {
        int rbase = rows0 + rt * 16 + ((lane >> 4) << 2);
        float dv[4];
#pragma unroll
        for (int r = 0; r < 4; ++r) dv[r] = dinv[rbase + r];
#pragma unroll
        for (int ct = 0; ct < 4; ++ct) {
            int col = ct * 16 + (lane & 15);
#pragma unroll
            for (int r = 0; r < 4; ++r)
                h1b[(size_t)(rbase + r) * 64 + col] = f2bf(acc[rt][ct][r] * dv[r]);
        }
    }
}

// ============ layer2 phase 1: partial[seg][v][64](bf16) = sum_seg h1b[src] ====
// XCD-pinned: seg = (blockIdx&7)>>1, so (with bid%8 -> XCD) each XCD gathers
// only from one <=4MB h1b slice -> L2-resident. 2 nodes/wave, quarter-wave
// per edge (uint2 8B covers 128B row).

__global__ __launch_bounds__(256) void aggseg_k(const int* __restrict__ soff,
        const int* __restrict__ offsets, const int* __restrict__ srt_src,
        const u16* __restrict__ h1b, u16* __restrict__ partial) {
    int t = threadIdx.x, lane = t & 63;
    int b = blockIdx.x;
    int r = b & 7;
    int seg = r >> 1;
    int ng = (b >> 3) * 2 + (r & 1);        // node-group in [0, N/8)
    int v0 = ng * 8 + (t >> 6) * 2;
    int v1 = v0 + 1;
    int f = lane & 15, q = lane >> 4;
    int i0 = soff[(size_t)v0 * 4 + seg];
    int e0 = (seg < 3) ? soff[(size_t)v0 * 4 + seg + 1] : offsets[v0 + 1];
    int i1 = soff[(size_t)v1 * 4 + seg];
    int e1 = (seg < 3) ? soff[(size_t)v1 * 4 + seg + 1] : offsets[v1 + 1];
    const uint2* rows = (const uint2*)h1b;  // row s = rows + s*16
    float a0 = 0.f, a1 = 0.f, a2 = 0.f, a3 = 0.f;
    float c0 = 0.f, c1 = 0.f, c2 = 0.f, c3 = 0.f;
    while (i0 + 4 <= e0 && i1 + 4 <= e1) {
        int sA = srt_src[i0 + q];
        int sC = srt_src[i1 + q];
        uint2 pA = rows[sA * 16 + f];
        uint2 pC = rows[sC * 16 + f];
        acc2(pA.x, a0, a1); acc2(pA.y, a2, a3);
        acc2(pC.x, c0, c1); acc2(pC.y, c2, c3);
        i0 += 4; i1 += 4;
    }
    for (; i0 + 4 <= e0; i0 += 4) {
        int s = srt_src[i0 + q];
        uint2 p = rows[s * 16 + f];
        acc2(p.x, a0, a1); acc2(p.y, a2, a3);
    }
    if (i0 + q < e0) {
        int s = srt_src[i0 + q];
        uint2 p = rows[s * 16 + f];
        acc2(p.x, a0, a1); acc2(p.y, a2, a3);
    }
    for (; i1 + 4 <= e1; i1 += 4) {
        int s = srt_src[i1 + q];
        uint2 p = rows[s * 16 + f];
        acc2(p.x, c0, c1); acc2(p.y, c2, c3);
    }
    if (i1 + q < e1) {
        int s = srt_src[i1 + q];
        uint2 p = rows[s * 16 + f];
        acc2(p.x, c0, c1); acc2(p.y, c2, c3);
    }
    a0 += __shfl_xor(a0, 16, 64); a0 += __shfl_xor(a0, 32, 64);
    a1 += __shfl_xor(a1, 16, 64); a1 += __shfl_xor(a1, 32, 64);
    a2 += __shfl_xor(a2, 16, 64); a2 += __shfl_xor(a2, 32, 64);
    a3 += __shfl_xor(a3, 16, 64); a3 += __shfl_xor(a3, 32, 64);
    c0 += __shfl_xor(c0, 16, 64); c0 += __shfl_xor(c0, 32, 64);
    c1 += __shfl_xor(c1, 16, 64); c1 += __shfl_xor(c1, 32, 64);
    c2 += __shfl_xor(c2, 16, 64); c2 += __shfl_xor(c2, 32, 64);
    c3 += __shfl_xor(c3, 16, 64); c3 += __shfl_xor(c3, 32, 64);
    bool lo = (lane < 32);
    int v = lo ? v0 : v1;
    float t0 = lo ? a0 : c0;
    float t1 = lo ? a1 : c1;
    float t2 = lo ? a2 : c2;
    float t3 = lo ? a3 : c3;
    if ((lane & 31) < 16) {
        u32 xw = (u32)f2bf(t0) | ((u32)f2bf(t1) << 16);
        u32 yw = (u32)f2bf(t2) | ((u32)f2bf(t3) << 16);
        ((uint2*)partial)[((size_t)seg * N_NODES + v) * 16 + (lane & 15)] =
            make_uint2(xw, yw);
    }
}

// ============ layer2 phase 2: h2b = dinv*(relu(dinv*sum(partials)+b1) @ W2) ==

__global__ __launch_bounds__(256) void l2fin_k(const u16* __restrict__ partial,
        const float* __restrict__ dinv, const float* __restrict__ b1,
        const float* __restrict__ W2, u16* __restrict__ h2b) {
    __shared__ float W2s[64 * 32];
    __shared__ float b1s[64];
    for (int i = threadIdx.x; i < 64 * 32; i += 256) W2s[i] = W2[i];
    if (threadIdx.x < 64) b1s[threadIdx.x] = b1[threadIdx.x];
    __syncthreads();
    int t = threadIdx.x, lane = t & 63;
    int half = lane >> 5, fl = lane & 31;
    int v = blockIdx.x * 8 + (t >> 6) * 2 + half;    // grid = N/8
    const u32* prow = (const u32*)partial;
    float r0 = 0.f, r1 = 0.f;
#pragma unroll
    for (int s = 0; s < 4; ++s) {
        u32 u = prow[((size_t)s * N_NODES + v) * 32 + fl];
        r0 += bf2f_u((u16)(u & 0xffff));
        r1 += bf2f_u((u16)(u >> 16));
    }
    float dv = dinv[v];
    r0 = fmaxf(fmaf(dv, r0, b1s[2 * fl]), 0.f);
    r1 = fmaxf(fmaf(dv, r1, b1s[2 * fl + 1]), 0.f);
    float o = 0.f;
#pragma unroll
    for (int g = 0; g < 32; ++g) {
        float R0 = __shfl(r0, g, 32);
        float R1 = __shfl(r1, g, 32);
        o = fmaf(R0, W2s[(2 * g) * 32 + fl], o);
        o = fmaf(R1, W2s[(2 * g + 1) * 32 + fl], o);
    }
    h2b[(size_t)v * 32 + fl] = f2bf(dv * o);
}

// ============ layer3: out = relu(dinv*agg(h2b) + b2) @ Wfc + bfc ============

#define GATH3(ii, A, B, C, D) { \
    int s_ = srt_src[(ii) + oc]; \
    uint2 p_ = rows[s_ * 8 + f]; \
    acc2(p_.x, A, B); acc2(p_.y, C, D); }

__global__ __launch_bounds__(256) void layer3_k(const int* __restrict__ offsets,
        const int* __restrict__ srt_src, const float* __restrict__ dinv,
        const u16* __restrict__ h2b, const float* __restrict__ b2,
        const float* __restrict__ Wfc, const float* __restrict__ bfc,
        float* __restrict__ out) {
    int lane = threadIdx.x & 63;
    int f = lane & 7, oc = lane >> 3;
    int vb = blockIdx.x * 16 + (threadIdx.x >> 6) * 4;   // grid = N/16
    int o0 = offsets[vb], o1 = offsets[vb + 1], o2 = offsets[vb + 2];
    int o3 = offsets[vb + 3], o4 = offsets[vb + 4];
    int i0 = o0, e0 = o1, i1 = o1, e1 = o2, i2 = o2, e2 = o3, i3 = o3, e3 = o4;
    const uint2* rows = (const uint2*)h2b;               // row s = rows + s*8
    float A0=0.f,A1=0.f,A2=0.f,A3=0.f, B0=0.f,B1=0.f,B2=0.f,B3=0.f;
    float C0=0.f,C1=0.f,C2=0.f,C3=0.f, D0=0.f,D1=0.f,D2=0.f,D3=0.f;
    while (i0 + 8 <= e0 && i1 + 8 <= e1 && i2 + 8 <= e2 && i3 + 8 <= e3) {
        GATH3(i0, A0, A1, A2, A3);
        GATH3(i1, B0, B1, B2, B3);
        GATH3(i2, C0, C1, C2, C3);
        GATH3(i3, D0, D1, D2, D3);
        i0 += 8; i1 += 8; i2 += 8; i3 += 8;
    }
    while (i0 + 8 <= e0) { GATH3(i0, A0, A1, A2, A3); i0 += 8; }
    if (i0 + oc < e0)    { GATH3(i0, A0, A1, A2, A3); }
    while (i1 + 8 <= e1) { GATH3(i1, B0, B1, B2, B3); i1 += 8; }
    if (i1 + oc < e1)    { GATH3(i1, B0, B1, B2, B3); }
    while (i2 + 8 <= e2) { GATH3(i2, C0, C1, C2, C3); i2 += 8; }
    if (i2 + oc < e2)    { GATH3(i2, C0, C1, C2, C3); }
    while (i3 + 8 <= e3) { GATH3(i3, D0, D1, D2, D3); i3 += 8; }
    if (i3 + oc < e3)    { GATH3(i3, D0, D1, D2, D3); }
#define RED3(X) X += __shfl_xor(X, 8, 64); X += __shfl_xor(X, 16, 64); X += __shfl_xor(X, 32, 64)
    RED3(A0); RED3(A1); RED3(A2); RED3(A3);
    RED3(B0); RED3(B1); RED3(B2); RED3(B3);
    RED3(C0); RED3(C1); RED3(C2); RED3(C3);
    RED3(D0); RED3(D1); RED3(D2); RED3(D3);
    float w0 = Wfc[4 * f + 0], w1 = Wfc[4 * f + 1];
    float w2 = Wfc[4 * f + 2], w3 = Wfc[4 * f + 3];
    float g0 = b2[4 * f + 0], g1 = b2[4 * f + 1];
    float g2 = b2[4 * f + 2], g3 = b2[4 * f + 3];
    float dv0 = dinv[vb], dv1 = dinv[vb + 1], dv2 = dinv[vb + 2], dv3 = dinv[vb + 3];
    float p0 = fmaxf(fmaf(dv0, A0, g0), 0.f) * w0 + fmaxf(fmaf(dv0, A1, g1), 0.f) * w1
             + fmaxf(fmaf(dv0, A2, g2), 0.f) * w2 + fmaxf(fmaf(dv0, A3, g3), 0.f) * w3;
    float p1 = fmaxf(fmaf(dv1, B0, g0), 0.f) * w0 + fmaxf(fmaf(dv1, B1, g1), 0.f) * w1
             + fmaxf(fmaf(dv1, B2, g2), 0.f) * w2 + fmaxf(fmaf(dv1, B3, g3), 0.f) * w3;
    float p2 = fmaxf(fmaf(dv2, C0, g0), 0.f) * w0 + fmaxf(fmaf(dv2, C1, g1), 0.f) * w1
             + fmaxf(fmaf(dv2, C2, g2), 0.f) * w2 + fmaxf(fmaf(dv2, C3, g3), 0.f) * w3;
    float p3 = fmaxf(fmaf(dv3, D0, g0), 0.f) * w0 + fmaxf(fmaf(dv3, D1, g1), 0.f) * w1
             + fmaxf(fmaf(dv3, D2, g2), 0.f) * w2 + fmaxf(fmaf(dv3, D3, g3), 0.f) * w3;
#define REDP(X) X += __shfl_xor(X, 1, 64); X += __shfl_xor(X, 2, 64); X += __shfl_xor(X, 4, 64)
    REDP(p0); REDP(p1); REDP(p2); REDP(p3);
    if (lane == 0) {
        float bb = bfc[0];
        out[vb + 0] = p0 + bb;
        out[vb + 1] = p1 + bb;
        out[vb + 2] = p2 + bb;
        out[vb + 3] = p3 + bb;
    }
}

// ============ launch ============

extern "C" void kernel_launch(void* const* d_in, const int* in_sizes, int n_in,
                              void* d_out, int out_size, void* d_ws, size_t ws_size,
                              hipStream_t stream) {
    const float* x   = (const float*)d_in[0];
    const int*   ei  = (const int*)d_in[1];
    const float* W1  = (const float*)d_in[2];
    const float* b1  = (const float*)d_in[3];
    const float* W2  = (const float*)d_in[4];
    const float* b2  = (const float*)d_in[5];
    const float* Wfc = (const float*)d_in[6];
    const float* bfc = (const float*)d_in[7];
    float* out = (float*)d_out;

    const int E = in_sizes[1] / 2;
    const int TOT = E + N_NODES;
    const int* src = ei;
    const int* dst = ei + E;

    // workspace layout: small tables | offsets | soff | srt_src | dinv |
    //                   h1b | h2b | partial (aliases bktBuf region)
    int*   ccount  = (int*)d_ws;                   // 256
    int*   cbase   = ccount + 256;                 // 256 (NBKT+1 used)
    int*   bcur    = cbase + 256;                  // 256
    int*   offsets = bcur + 256;                   // N+1
    int*   soff    = offsets + N_NODES + 1;        // 4N
    int*   srt_src = soff + 4 * N_NODES;           // TOT
    float* dinv    = (float*)(srt_src + TOT);      // N
    u16*   h1b     = (u16*)(dinv + N_NODES);       // 64N bf16
    u16*   h2b     = h1b + (size_t)N_NODES * 64;   // 32N bf16
    // align to 8B
    size_t tail = ((size_t)(h2b + (size_t)N_NODES * 32 - (u16*)d_ws) + 3) & ~(size_t)3;
    u16*   partial = (u16*)d_ws + tail;            // NSEG*64N bf16 (51.2MB)
    uint2* bktBuf  = (uint2*)partial;              // TOT uint2 (13.6MB, dead after buildfill)

    const int NCH = (TOT + CH - 1) / CH;

    hipMemsetAsync(ccount, 0, 256 * sizeof(int), stream);
    coarsehist_k<<<NCH, 256, 0, stream>>>(dst, ccount, E, TOT);
    coarsescan_k<<<1, 256, 0, stream>>>(ccount, cbase, bcur, offsets);
    partition_k<<<NCH, 256, 0, stream>>>(src, dst, bcur, bktBuf, E, TOT);
    buildfill_k<<<NBKT, 256, 0, stream>>>(cbase, bktBuf, offsets, soff, dinv, srt_src);

    const int GB1 = (N_NODES / 32 + 3) / 4;   // 782 blocks x 4 waves x 32 rows
    gemm1_k<<<GB1, 256, 0, stream>>>(x, W1, dinv, h1b);

    aggseg_k<<<NSEG * (N_NODES / 8), 256, 0, stream>>>(soff, offsets, srt_src,
                                                       h1b, partial);
    l2fin_k<<<N_NODES / 8, 256, 0, stream>>>(partial, dinv, b1, W2, h2b);
    layer3_k<<<N_NODES / 16, 256, 0, stream>>>(offsets, srt_src, dinv, h2b, b2, Wfc,
                                               bfc, out);
}

// Round 11
// 187.710 us; speedup vs baseline: 1.3474x; 1.3474x over previous
//
#include <hip/hip_runtime.h>

#define N_NODES 100000
#define BSH 9                           // 512 nodes per bucket
#define NBKT ((N_NODES + 511) >> BSH)   // 196
#define CH 7168                         // items per partition chunk
#define SLACK 10240                     // per-bucket slack allocation

typedef unsigned int u32;
typedef unsigned short u16;
typedef unsigned char u8;
typedef __attribute__((ext_vector_type(8))) short s8v;   // 8 bf16 (4 VGPRs)
typedef __attribute__((ext_vector_type(4))) float f4v;   // 4 f32 acc

static __device__ __forceinline__ u16 f2bf(float f) {  // round-nearest-even
    union { float f; u32 u; } c; c.f = f;
    u32 r = (c.u + 0x7fffu + ((c.u >> 16) & 1u)) >> 16;
    return (u16)r;
}
static __device__ __forceinline__ float bf2f_u(u16 h) {
    union { u32 u; float f; } c; c.u = ((u32)h) << 16;
    return c.f;
}
static __device__ __forceinline__ void acc2(u32 p, float& a, float& b) {
    union { u32 u; float f; } lo, hi;
    lo.u = p << 16;
    hi.u = p & 0xffff0000u;
    a += lo.f;
    b += hi.f;
}
static __device__ __forceinline__ void acc8(uint4 p, float* a) {
    acc2(p.x, a[0], a[1]); acc2(p.y, a[2], a[3]);
    acc2(p.z, a[4], a[5]); acc2(p.w, a[6], a[7]);
}

// ============ CSR build (slack buckets, packed items) ============
// item e in [0,E) = edge (src[e],dst[e]); e in [E,E+N) = self-loop (v,v).
// packed item = ((dst & 511) << 17) | src    (src < 2^17)

__global__ __launch_bounds__(256) void initcur_k(int* __restrict__ bcur) {
    bcur[threadIdx.x] = threadIdx.x * SLACK;
}

// chunked LDS counting-sort partition -> bktBuf runs (per-bucket slack space)
__global__ __launch_bounds__(256) void partition_k(const int* __restrict__ src,
        const int* __restrict__ dst, int* __restrict__ bcur,
        u32* __restrict__ bktBuf, int E, int TOT) {
    __shared__ int hist[256];
    __shared__ int lbase[256];
    __shared__ int gbase[256];
    __shared__ int ps[256];
    __shared__ u32 stage[CH];
    __shared__ u8 stageB[CH];
    int t = threadIdx.x;
    int base = blockIdx.x * CH;
    int cnt = min(CH, TOT - base);
    hist[t] = 0;
    __syncthreads();
    // pass A: bucket counts
    for (int i = t; i < cnt; i += 256) {
        int e = base + i;
        int d = (e < E) ? dst[e] : e - E;
        atomicAdd(&hist[d >> BSH], 1);
    }
    __syncthreads();
    // scan -> local bases; reserve global runs
    ps[t] = hist[t];
    __syncthreads();
    for (int off = 1; off < 256; off <<= 1) {
        int val = ps[t];
        int add = (t >= off) ? ps[t - off] : 0;
        __syncthreads();
        ps[t] = val + add;
        __syncthreads();
    }
    lbase[t] = ps[t] - hist[t];
    gbase[t] = atomicAdd(&bcur[t], hist[t]);
    hist[t] = 0;                 // reuse as local cursor
    __syncthreads();
    // pass B: stage bucket-sorted in LDS
    for (int i = t; i < cnt; i += 256) {
        int e = base + i;
        int s, d;
        if (e < E) { s = src[e]; d = dst[e]; }
        else       { s = d = e - E; }
        int b = d >> BSH;
        int lpos = lbase[b] + atomicAdd(&hist[b], 1);
        stage[lpos] = ((u32)(d & 511) << 17) | (u32)s;
        stageB[lpos] = (u8)b;
    }
    __syncthreads();
    // pass C: contiguous run writes
    for (int i = t; i < cnt; i += 256) {
        int b = stageB[i];
        bktBuf[gbase[b] + (i - lbase[b])] = stage[i];
    }
}

// one block per bucket: local deg histogram+scan -> offsets, ends, dinv;
// scatter srt_src inside the block-exclusive slack window.
__global__ __launch_bounds__(256) void buildfill_k(const int* __restrict__ bcur,
        const u32* __restrict__ bktBuf, int* __restrict__ offsets,
        int* __restrict__ ends, float* __restrict__ dinv,
        int* __restrict__ srt_src) {
    __shared__ int hist[512];
    __shared__ int hscan[512];
    __shared__ int cur[512];
    __shared__ int ps[256];
    int t = threadIdx.x;
    int b = blockIdx.x;
    int v0 = b << BSH;
    int nv = min(512, N_NODES - v0);
    int base = b * SLACK;
    int cnt = bcur[b] - base;
    hist[t] = 0; hist[t + 256] = 0;
    cur[t] = 0;  cur[t + 256] = 0;
    __syncthreads();
    for (int i = t; i < cnt; i += 256)
        atomicAdd(&hist[bktBuf[base + i] >> 17], 1);
    __syncthreads();
    // exclusive scan of hist[0..511] (pairs + Hillis-Steele over 256)
    int a = hist[2 * t], bb = hist[2 * t + 1];
    int own = a + bb;
    ps[t] = own;
    __syncthreads();
    for (int off = 1; off < 256; off <<= 1) {
        int val = ps[t];
        int add = (t >= off) ? ps[t - off] : 0;
        __syncthreads();
        ps[t] = val + add;
        __syncthreads();
    }
    int excl2 = ps[t] - own;
    hscan[2 * t] = excl2;
    hscan[2 * t + 1] = excl2 + a;
    __syncthreads();
    // offsets/ends + dinv (hist includes the self-loop -> deg+1)
    for (int j = t; j < nv; j += 256) {
        int o = base + hscan[j];
        offsets[v0 + j] = o;
        ends[v0 + j] = o + hist[j];
        dinv[v0 + j] = rsqrtf((float)hist[j]);
    }
    // scatter within slack window — block-exclusive
    for (int i = t; i < cnt; i += 256) {
        u32 it = bktBuf[base + i];
        int j = it >> 17;
        int pos = atomicAdd(&cur[j], 1);
        srt_src[base + hscan[j] + pos] = (int)(it & 0x1ffffu);
    }
}

// ============ GEMM1 (MFMA): h1b[N,64](bf16) = dinv[row] * (x[N,128] @ W1) ====

static __device__ __forceinline__ void split8(const float* __restrict__ xp,
                                              s8v& hi, s8v& lo) {
    float4 v0 = *(const float4*)xp;
    float4 v1 = *(const float4*)(xp + 4);
    float xv[8] = {v0.x, v0.y, v0.z, v0.w, v1.x, v1.y, v1.z, v1.w};
#pragma unroll
    for (int j = 0; j < 8; ++j) {
        u16 h = f2bf(xv[j]);
        hi[j] = (short)h;
        lo[j] = (short)f2bf(xv[j] - bf2f_u(h));
    }
}

__global__ __launch_bounds__(256) void gemm1_k(const float* __restrict__ x,
                                               const float* __restrict__ W1,
                                               const float* __restrict__ dinv,
                                               u16* __restrict__ h1b) {
    __shared__ __attribute__((aligned(16))) short Bs[2][4][4][512];
    int t = threadIdx.x;
    for (int i = t; i < 128 * 64; i += 256) {
        int k = i >> 6, c = i & 63;
        float w = W1[i];
        u16 h = f2bf(w);
        u16 l = f2bf(w - bf2f_u(h));
        int ks = k >> 5, kg = (k >> 3) & 3, kk = k & 7;
        int ct = c >> 4, col = c & 15;
        int idx = (kg * 16 + col) * 8 + kk;
        Bs[0][ks][ct][idx] = (short)h;
        Bs[1][ks][ct][idx] = (short)l;
    }
    __syncthreads();

    int lane = t & 63;
    int rows0 = (blockIdx.x * 4 + (t >> 6)) * 32;
    if (rows0 >= N_NODES) return;

    f4v acc[2][4];
#pragma unroll
    for (int rt = 0; rt < 2; ++rt)
#pragma unroll
        for (int ct = 0; ct < 4; ++ct)
            acc[rt][ct] = (f4v){0.f, 0.f, 0.f, 0.f};

    int arow = lane & 15;
    int kgl = lane >> 4;
#pragma unroll
    for (int ks = 0; ks < 4; ++ks) {
        s8v bh[4], bl[4];
#pragma unroll
        for (int ct = 0; ct < 4; ++ct) {
            bh[ct] = *(const s8v*)&Bs[0][ks][ct][lane * 8];
            bl[ct] = *(const s8v*)&Bs[1][ks][ct][lane * 8];
        }
#pragma unroll
        for (int rt = 0; rt < 2; ++rt) {
            s8v ah, al;
            const float* xp = x + (size_t)(rows0 + rt * 16 + arow) * 128
                                + ks * 32 + kgl * 8;
            split8(xp, ah, al);
#pragma unroll
            for (int ct = 0; ct < 4; ++ct) {
                acc[rt][ct] = __builtin_amdgcn_mfma_f32_16x16x32_bf16(
                    ah, bh[ct], acc[rt][ct], 0, 0, 0);
                acc[rt][ct] = __builtin_amdgcn_mfma_f32_16x16x32_bf16(
                    ah, bl[ct], acc[rt][ct], 0, 0, 0);
                acc[rt][ct] = __builtin_amdgcn_mfma_f32_16x16x32_bf16(
                    al, bh[ct], acc[rt][ct], 0, 0, 0);
            }
        }
    }

#pragma unroll
    for (int rt = 0; rt < 2; ++rt) {
        int rbase = rows0 + rt * 16 + ((lane >> 4) << 2);
        float dv[4];
#pragma unroll
        for (int r = 0; r < 4; ++r) dv[r] = dinv[rbase + r];
#pragma unroll
        for (int ct = 0; ct < 4; ++ct) {
            int col = ct * 16 + (lane & 15);
#pragma unroll
            for (int r = 0; r < 4; ++r)
                h1b[(size_t)(rbase + r) * 64 + col] = f2bf(acc[rt][ct][r] * dv[r]);
        }
    }
}

// ============ layer2: h2b = dinv * (relu(dinv*agg + b1) @ W2)  (R8 form) ====

__global__ __launch_bounds__(256) void layer2_k(const int* __restrict__ offsets,
        const int* __restrict__ ends, const int* __restrict__ srt_src,
        const float* __restrict__ dinv, const u16* __restrict__ h1b,
        const float* __restrict__ b1, const float* __restrict__ W2,
        u16* __restrict__ h2b) {
    __shared__ float W2s[64 * 32];
    __shared__ float b1s[64];
    for (int i = threadIdx.x; i < 64 * 32; i += 256) W2s[i] = W2[i];
    if (threadIdx.x < 64) b1s[threadIdx.x] = b1[threadIdx.x];
    __syncthreads();
    int lane = threadIdx.x & 63;
    int f = lane & 15, q = lane >> 4;
    int v0 = blockIdx.x * 8 + (threadIdx.x >> 6) * 2;   // grid = N/8
    int v1 = v0 + 1;
    int i0 = offsets[v0], e0 = ends[v0];
    int i1 = offsets[v1], e1 = ends[v1];
    const uint2* rows = (const uint2*)h1b;              // row s = rows + s*16
    float a0 = 0.f, a1 = 0.f, a2 = 0.f, a3 = 0.f;       // node0
    float c0 = 0.f, c1 = 0.f, c2 = 0.f, c3 = 0.f;       // node1
    while (i0 + 8 <= e0 && i1 + 8 <= e1) {
        int sA = srt_src[i0 + q];
        int sB = srt_src[i0 + 4 + q];
        int sC = srt_src[i1 + q];
        int sD = srt_src[i1 + 4 + q];
        uint2 pA = rows[sA * 16 + f];
        uint2 pB = rows[sB * 16 + f];
        uint2 pC = rows[sC * 16 + f];
        uint2 pD = rows[sD * 16 + f];
        acc2(pA.x, a0, a1); acc2(pA.y, a2, a3);
        acc2(pB.x, a0, a1); acc2(pB.y, a2, a3);
        acc2(pC.x, c0, c1); acc2(pC.y, c2, c3);
        acc2(pD.x, c0, c1); acc2(pD.y, c2, c3);
        i0 += 8; i1 += 8;
    }
    for (; i0 + 8 <= e0; i0 += 8) {
        int sA = srt_src[i0 + q], sB = srt_src[i0 + 4 + q];
        uint2 pA = rows[sA * 16 + f], pB = rows[sB * 16 + f];
        acc2(pA.x, a0, a1); acc2(pA.y, a2, a3);
        acc2(pB.x, a0, a1); acc2(pB.y, a2, a3);
    }
    for (; i0 < e0; i0 += 4) {
        int j = i0 + q;
        if (j < e0) {
            int s = srt_src[j];
            uint2 p = rows[s * 16 + f];
            acc2(p.x, a0, a1); acc2(p.y, a2, a3);
        }
    }
    for (; i1 + 8 <= e1; i1 += 8) {
        int sA = srt_src[i1 + q], sB = srt_src[i1 + 4 + q];
        uint2 pA = rows[sA * 16 + f], pB = rows[sB * 16 + f];
        acc2(pA.x, c0, c1); acc2(pA.y, c2, c3);
        acc2(pB.x, c0, c1); acc2(pB.y, c2, c3);
    }
    for (; i1 < e1; i1 += 4) {
        int j = i1 + q;
        if (j < e1) {
            int s = srt_src[j];
            uint2 p = rows[s * 16 + f];
            acc2(p.x, c0, c1); acc2(p.y, c2, c3);
        }
    }
    a0 += __shfl_xor(a0, 16, 64); a0 += __shfl_xor(a0, 32, 64);
    a1 += __shfl_xor(a1, 16, 64); a1 += __shfl_xor(a1, 32, 64);
    a2 += __shfl_xor(a2, 16, 64); a2 += __shfl_xor(a2, 32, 64);
    a3 += __shfl_xor(a3, 16, 64); a3 += __shfl_xor(a3, 32, 64);
    c0 += __shfl_xor(c0, 16, 64); c0 += __shfl_xor(c0, 32, 64);
    c1 += __shfl_xor(c1, 16, 64); c1 += __shfl_xor(c1, 32, 64);
    c2 += __shfl_xor(c2, 16, 64); c2 += __shfl_xor(c2, 32, 64);
    c3 += __shfl_xor(c3, 16, 64); c3 += __shfl_xor(c3, 32, 64);
    bool lo = (lane < 32);
    float dv = lo ? dinv[v0] : dinv[v1];
    float t0 = lo ? a0 : c0;
    float t1 = lo ? a1 : c1;
    float t2 = lo ? a2 : c2;
    float t3 = lo ? a3 : c3;
    float r0 = fmaxf(fmaf(dv, t0, b1s[4 * f + 0]), 0.f);
    float r1 = fmaxf(fmaf(dv, t1, b1s[4 * f + 1]), 0.f);
    float r2 = fmaxf(fmaf(dv, t2, b1s[4 * f + 2]), 0.f);
    float r3 = fmaxf(fmaf(dv, t3, b1s[4 * f + 3]), 0.f);
    int c = lane & 31;
    float o = 0.f;
#pragma unroll
    for (int j2 = 0; j2 < 16; ++j2) {
        float R0 = __shfl(r0, j2, 16);
        float R1 = __shfl(r1, j2, 16);
        float R2 = __shfl(r2, j2, 16);
        float R3 = __shfl(r3, j2, 16);
        o = fmaf(R0, W2s[(4 * j2 + 0) * 32 + c], o);
        o = fmaf(R1, W2s[(4 * j2 + 1) * 32 + c], o);
        o = fmaf(R2, W2s[(4 * j2 + 2) * 32 + c], o);
        o = fmaf(R3, W2s[(4 * j2 + 3) * 32 + c], o);
    }
    int vst = lo ? v0 : v1;
    h2b[vst * 32 + c] = f2bf(dv * o);
}

// ============ layer3: out = relu(dinv*agg(h2b) + b2) @ Wfc + bfc  (R8 form) ==

#define GATH3(ii, A, B, C, D) { \
    int s_ = srt_src[(ii) + oc]; \
    uint2 p_ = rows[s_ * 8 + f]; \
    acc2(p_.x, A, B); acc2(p_.y, C, D); }

__global__ __launch_bounds__(256) void layer3_k(const int* __restrict__ offsets,
        const int* __restrict__ ends, const int* __restrict__ srt_src,
        const float* __restrict__ dinv, const u16* __restrict__ h2b,
        const float* __restrict__ b2, const float* __restrict__ Wfc,
        const float* __restrict__ bfc, float* __restrict__ out) {
    int lane = threadIdx.x & 63;
    int f = lane & 7, oc = lane >> 3;
    int vb = blockIdx.x * 16 + (threadIdx.x >> 6) * 4;   // grid = N/16
    int i0 = offsets[vb],     e0 = ends[vb];
    int i1 = offsets[vb + 1], e1 = ends[vb + 1];
    int i2 = offsets[vb + 2], e2 = ends[vb + 2];
    int i3 = offsets[vb + 3], e3 = ends[vb + 3];
    const uint2* rows = (const uint2*)h2b;               // row s = rows + s*8
    float A0=0.f,A1=0.f,A2=0.f,A3=0.f, B0=0.f,B1=0.f,B2=0.f,B3=0.f;
    float C0=0.f,C1=0.f,C2=0.f,C3=0.f, D0=0.f,D1=0.f,D2=0.f,D3=0.f;
    while (i0 + 8 <= e0 && i1 + 8 <= e1 && i2 + 8 <= e2 && i3 + 8 <= e3) {
        GATH3(i0, A0, A1, A2, A3);
        GATH3(i1, B0, B1, B2, B3);
        GATH3(i2, C0, C1, C2, C3);
        GATH3(i3, D0, D1, D2, D3);
        i0 += 8; i1 += 8; i2 += 8; i3 += 8;
    }
    while (i0 + 8 <= e0) { GATH3(i0, A0, A1, A2, A3); i0 += 8; }
    if (i0 + oc < e0)    { GATH3(i0, A0, A1, A2, A3); }
    while (i1 + 8 <= e1) { GATH3(i1, B0, B1, B2, B3); i1 += 8; }
    if (i1 + oc < e1)    { GATH3(i1, B0, B1, B2, B3); }
    while (i2 + 8 <= e2) { GATH3(i2, C0, C1, C2, C3); i2 += 8; }
    if (i2 + oc < e2)    { GATH3(i2, C0, C1, C2, C3); }
    while (i3 + 8 <= e3) { GATH3(i3, D0, D1, D2, D3); i3 += 8; }
    if (i3 + oc < e3)    { GATH3(i3, D0, D1, D2, D3); }
#define RED3(X) X += __shfl_xor(X, 8, 64); X += __shfl_xor(X, 16, 64); X += __shfl_xor(X, 32, 64)
    RED3(A0); RED3(A1); RED3(A2); RED3(A3);
    RED3(B0); RED3(B1); RED3(B2); RED3(B3);
    RED3(C0); RED3(C1); RED3(C2); RED3(C3);
    RED3(D0); RED3(D1); RED3(D2); RED3(D3);
    float w0 = Wfc[4 * f + 0], w1 = Wfc[4 * f + 1];
    float w2 = Wfc[4 * f + 2], w3 = Wfc[4 * f + 3];
    float g0 = b2[4 * f + 0], g1 = b2[4 * f + 1];
    float g2 = b2[4 * f + 2], g3 = b2[4 * f + 3];
    float dv0 = dinv[vb], dv1 = dinv[vb + 1], dv2 = dinv[vb + 2], dv3 = dinv[vb + 3];
    float p0 = fmaxf(fmaf(dv0, A0, g0), 0.f) * w0 + fmaxf(fmaf(dv0, A1, g1), 0.f) * w1
             + fmaxf(fmaf(dv0, A2, g2), 0.f) * w2 + fmaxf(fmaf(dv0, A3, g3), 0.f) * w3;
    float p1 = fmaxf(fmaf(dv1, B0, g0), 0.f) * w0 + fmaxf(fmaf(dv1, B1, g1), 0.f) * w1
             + fmaxf(fmaf(dv1, B2, g2), 0.f) * w2 + fmaxf(fmaf(dv1, B3, g3), 0.f) * w3;
    float p2 = fmaxf(fmaf(dv2, C0, g0), 0.f) * w0 + fmaxf(fmaf(dv2, C1, g1), 0.f) * w1
             + fmaxf(fmaf(dv2, C2, g2), 0.f) * w2 + fmaxf(fmaf(dv2, C3, g3), 0.f) * w3;
    float p3 = fmaxf(fmaf(dv3, D0, g0), 0.f) * w0 + fmaxf(fmaf(dv3, D1, g1), 0.f) * w1
             + fmaxf(fmaf(dv3, D2, g2), 0.f) * w2 + fmaxf(fmaf(dv3, D3, g3), 0.f) * w3;
#define REDP(X) X += __shfl_xor(X, 1, 64); X += __shfl_xor(X, 2, 64); X += __shfl_xor(X, 4, 64)
    REDP(p0); REDP(p1); REDP(p2); REDP(p3);
    if (lane == 0) {
        float bb = bfc[0];
        out[vb + 0] = p0 + bb;
        out[vb + 1] = p1 + bb;
        out[vb + 2] = p2 + bb;
        out[vb + 3] = p3 + bb;
    }
}

// ============ launch ============

extern "C" void kernel_launch(void* const* d_in, const int* in_sizes, int n_in,
                              void* d_out, int out_size, void* d_ws, size_t ws_size,
                              hipStream_t stream) {
    const float* x   = (const float*)d_in[0];
    const int*   ei  = (const int*)d_in[1];
    const float* W1  = (const float*)d_in[2];
    const float* b1  = (const float*)d_in[3];
    const float* W2  = (const float*)d_in[4];
    const float* b2  = (const float*)d_in[5];
    const float* Wfc = (const float*)d_in[6];
    const float* bfc = (const float*)d_in[7];
    float* out = (float*)d_out;

    const int E = in_sizes[1] / 2;
    const int TOT = E + N_NODES;
    const int* src = ei;
    const int* dst = ei + E;

    // workspace layout (ints)
    int*   bcur    = (int*)d_ws;                       // 256
    int*   offsets = bcur + 256;                       // N
    int*   ends    = offsets + N_NODES;                // N
    int*   srt_src = ends + N_NODES;                   // NBKT*SLACK (~2.0M)
    u32*   bktBuf  = (u32*)(srt_src + NBKT * SLACK);   // NBKT*SLACK
    float* dinv    = (float*)(bktBuf + NBKT * SLACK);  // N
    u16*   h1b     = (u16*)(dinv + N_NODES);           // 64N bf16
    u16*   h2b     = h1b + (size_t)N_NODES * 64;       // 32N bf16

    const int NCH = (TOT + CH - 1) / CH;

    initcur_k<<<1, 256, 0, stream>>>(bcur);
    partition_k<<<NCH, 256, 0, stream>>>(src, dst, bcur, bktBuf, E, TOT);
    buildfill_k<<<NBKT, 256, 0, stream>>>(bcur, bktBuf, offsets, ends, dinv,
                                          srt_src);

    const int GB1 = (N_NODES / 32 + 3) / 4;   // 782 blocks x 4 waves x 32 rows
    gemm1_k<<<GB1, 256, 0, stream>>>(x, W1, dinv, h1b);

    layer2_k<<<N_NODES / 8, 256, 0, stream>>>(offsets, ends, srt_src, dinv, h1b,
                                              b1, W2, h2b);
    layer3_k<<<N_NODES / 16, 256, 0, stream>>>(offsets, ends, srt_src, dinv, h2b,
                                               b2, Wfc, bfc, out);
}